// Round 5
// baseline (70.313 us; speedup 1.0000x reference)
//
#include <hip/hip_runtime.h>

// 5-qubit state, two patches per thread packed in float2 lanes (.x = patch0, .y = patch1).
// index = a*16 + b*8 + c*4 + d*2 + e ; wire0=a=bit4 ... wire4=e=bit0
// All gates are elementwise identical across the two packed patches -> v_pk_*_f32.
// PITFALL (rounds 2-3): neg_lo/neg_hi modifiers on v_pk_*_f32 inline asm do NOT
// behave as expected on gfx950 (bounded sign-error, absmax ~0.2-0.5).
// Use plain pk_fma/pk_mul with explicitly negated splat constants only.

typedef float f2 __attribute__((ext_vector_type(2)));

__device__ __forceinline__ f2 pk_fma(f2 a, f2 b, f2 c) {   // a*b + c
    f2 d; asm("v_pk_fma_f32 %0, %1, %2, %3" : "=v"(d) : "v"(a), "v"(b), "v"(c)); return d;
}
__device__ __forceinline__ f2 pk_mul(f2 a, f2 b) {          // a*b
    f2 d; asm("v_pk_mul_f32 %0, %1, %2" : "=v"(d) : "v"(a), "v"(b)); return d;
}
__device__ __forceinline__ f2 sp(float v) { f2 r; r.x = v; r.y = v; return r; }

// sin/cos of ang/2 via native v_sin/v_cos (input in revolutions; |rev|<0.5 here).
__device__ __forceinline__ void sc_half(float ang, float& s, float& c) {
    const float r = ang * 0.07957747154594767f;   // (ang/2) / (2*pi)
    s = __builtin_amdgcn_sinf(r);
    c = __builtin_amdgcn_cosf(r);
}
__device__ __forceinline__ void sc_full(float ang, float& s, float& c) {
    const float r = ang * 0.15915494309189535f;   // ang / (2*pi)
    s = __builtin_amdgcn_sinf(r);
    c = __builtin_amdgcn_cosf(r);
}
__device__ __forceinline__ void sc_half2(f2 ang, f2& s, f2& c) {
    float s0, c0, s1, c1;
    sc_half(ang.x, s0, c0);
    sc_half(ang.y, s1, c1);
    s.x = s0; s.y = s1; c.x = c0; c.y = c1;
}

template<int BIT>
__device__ __forceinline__ void apply_rx(f2 (&R)[32], f2 (&I)[32],
                                         f2 C, f2 S, f2 NS) {
    // gate [[c, -i*s], [-i*s, c]]  (elementwise over packed patch pair)
#pragma unroll
    for (int m = 0; m < 16; ++m) {
        const int lo = m & ((1 << BIT) - 1);
        const int hi = (m >> BIT) << (BIT + 1);
        const int i0 = hi | lo;
        const int i1 = i0 | (1 << BIT);
        const f2 ar = R[i0], ai = I[i0];
        const f2 br = R[i1], bi = I[i1];
        R[i0] = pk_fma(C, ar, pk_mul(S,  bi));   //  c*ar + s*bi
        I[i0] = pk_fma(C, ai, pk_mul(NS, br));   //  c*ai - s*br
        R[i1] = pk_fma(C, br, pk_mul(S,  ai));   //  c*br + s*ai
        I[i1] = pk_fma(C, bi, pk_mul(NS, ar));   //  c*bi - s*ar
    }
}

// controlled-X_theta with u01 = sn - i*cs, u10 = -sn - i*cs (of theta/2).
// NB=8: lower-16 amps only (layer 0, wire-0 halves identical); NB=16: all 32.
template<int CBIT, int TBIT, int NB>
__device__ __forceinline__ void cu_gate(f2 (&R)[32], f2 (&I)[32],
                                        float sn, float cs) {
    const f2 S = sp(sn), NS = sp(-sn), C = sp(cs), NC = sp(-cs);
#pragma unroll
    for (int m = 0; m < NB; ++m) {
        const int lo = m & ((1 << TBIT) - 1);
        const int hi = (m >> TBIT) << (TBIT + 1);
        const int i0 = hi | lo;
        if (!(i0 & (1 << CBIT))) continue;   // compile-time eliminated
        const int i1 = i0 | (1 << TBIT);
        const f2 ar = R[i0], ai = I[i0];
        const f2 br = R[i1], bi = I[i1];
        R[i0] = pk_fma(S,  br, pk_mul(C,  bi));  //  sn*br + cs*bi
        I[i0] = pk_fma(S,  bi, pk_mul(NC, br));  //  sn*bi - cs*br
        R[i1] = pk_fma(NS, ar, pk_mul(C,  ai));  // -sn*ar + cs*ai
        I[i1] = pk_fma(NS, ai, pk_mul(NC, ar));  // -sn*ai - cs*ar
    }
}

__global__ __launch_bounds__(256, 3)
void qsim_kernel(const float* __restrict__ x,
                 const float* __restrict__ thetas,
                 const float* __restrict__ phis,
                 float* __restrict__ out, int P) {
    const int t = blockIdx.x * blockDim.x + threadIdx.x;
    const int T = P >> 1;                 // two patches per thread
    if (t >= T) return;

    // patches p0 = 2t, p1 = 2t+1 (adjacent j -> one float4 covers both)
    const int b  = t >> 13;
    const int i  = (t & 8191) >> 6;
    const int jt = t & 63;

    const float4* __restrict__ x4 = (const float4*)x;
    const long rowbase = (long)b * 768 + 2 * i;   // + c*256 + dy

    // ---- channel 0 loads ----
    float4 v0 = x4[(rowbase + 0) * 64 + jt];
    float4 v1 = x4[(rowbase + 1) * 64 + jt];

    // ---- fold H(wire0) + layer-0 RX into 16-amp product state ----
    // amp(bcde) = m(bcde) * (-i)^popcount(bcde); wire-0 halves identical.
    f2 R[32], I[32];
    {
        f2 a0 = {v0.x, v0.z}, a1 = {v0.y, v0.w};
        f2 a2 = {v1.x, v1.z}, a3 = {v1.y, v1.w};
        f2 s1, c1, s2, c2, s3, c3, s4, c4;
        sc_half2(a0, s1, c1);
        sc_half2(a1, s2, c2);
        sc_half2(a2, s3, c3);
        sc_half2(a3, s4, c4);
        f2 pA[4], pB[4];
        pA[0] = pk_mul(c1, c2); pA[1] = pk_mul(c1, s2);
        pA[2] = pk_mul(s1, c2); pA[3] = pk_mul(s1, s2);
        pB[0] = pk_mul(c3, c4); pB[1] = pk_mul(c3, s4);
        pB[2] = pk_mul(s3, c4); pB[3] = pk_mul(s3, s4);
#pragma unroll
        for (int m = 0; m < 16; ++m) {
            const f2 v  = pk_mul(pA[m >> 2], pB[m & 3]);
            const f2 nv = -v;
            const f2 z  = sp(0.f);
            const int pc = __builtin_popcount((unsigned)m) & 3;
            R[m] = (pc == 0) ? v  : ((pc == 2) ? nv : z);
            I[m] = (pc == 1) ? nv : ((pc == 3) ? v  : z);
        }
    }

    // issue channel-1 loads early (consumed in layer-1 RX)
    v0 = x4[(rowbase + 256) * 64 + jt];
    v1 = x4[(rowbase + 257) * 64 + jt];

    // ---- layer 0: CU gates on 16 amps (halves still identical) ----
    {
        float sn, cs;
        sc_half(thetas[0], sn, cs); cu_gate<3, 2, 8>(R, I, sn, cs);
        sc_half(thetas[1], sn, cs); cu_gate<2, 1, 8>(R, I, sn, cs);
        sc_half(thetas[2], sn, cs); cu_gate<1, 0, 8>(R, I, sn, cs);
        sc_half(thetas[3], sn, cs); cu_gate<0, 3, 8>(R, I, sn, cs);
    }

    // duplicate to wire0=1 half with CPhase(phi0) folded in (amps 24..31)
    {
        float snp, csp;
        sc_full(phis[0], snp, csp);
        const f2 C = sp(csp), S = sp(snp), NS = sp(-snp);
#pragma unroll
        for (int m = 0; m < 8; ++m) { R[m + 16] = R[m]; I[m + 16] = I[m]; }
#pragma unroll
        for (int m = 8; m < 16; ++m) {
            R[m + 16] = pk_fma(C, R[m], pk_mul(NS, I[m]));
            I[m + 16] = pk_fma(C, I[m], pk_mul(S,  R[m]));
        }
    }

    // ---- layer 1 ----
    {
        f2 a0 = {v0.x, v0.z}, a1 = {v0.y, v0.w};
        f2 a2 = {v1.x, v1.z}, a3 = {v1.y, v1.w};
        f2 S, C;
        sc_half2(a0, S, C); apply_rx<3>(R, I, C, S, -S);
        sc_half2(a1, S, C); apply_rx<2>(R, I, C, S, -S);
        sc_half2(a2, S, C); apply_rx<1>(R, I, C, S, -S);
        sc_half2(a3, S, C); apply_rx<0>(R, I, C, S, -S);
    }
    // issue channel-2 loads early (consumed in layer-2 RX)
    v0 = x4[(rowbase + 512) * 64 + jt];
    v1 = x4[(rowbase + 513) * 64 + jt];

    {
        float sn, cs;
        sc_half(thetas[4], sn, cs); cu_gate<3, 2, 16>(R, I, sn, cs);
        sc_half(thetas[5], sn, cs); cu_gate<2, 1, 16>(R, I, sn, cs);
        sc_half(thetas[6], sn, cs); cu_gate<1, 0, 16>(R, I, sn, cs);
        sc_half(thetas[7], sn, cs); cu_gate<0, 3, 16>(R, I, sn, cs);
    }
    {
        float snp, csp;
        sc_full(phis[1], snp, csp);
        const f2 C = sp(csp), S = sp(snp), NS = sp(-snp);
#pragma unroll
        for (int m = 24; m < 32; ++m) {
            const f2 r = R[m], ii = I[m];
            R[m] = pk_fma(C, r,  pk_mul(NS, ii));
            I[m] = pk_fma(C, ii, pk_mul(S,  r));
        }
    }

    // ---- layer 2 ----
    {
        f2 a0 = {v0.x, v0.z}, a1 = {v0.y, v0.w};
        f2 a2 = {v1.x, v1.z}, a3 = {v1.y, v1.w};
        f2 S, C;
        sc_half2(a0, S, C); apply_rx<3>(R, I, C, S, -S);
        sc_half2(a1, S, C); apply_rx<2>(R, I, C, S, -S);
        sc_half2(a2, S, C); apply_rx<1>(R, I, C, S, -S);
        sc_half2(a3, S, C); apply_rx<0>(R, I, C, S, -S);
    }
    {
        float sn, cs;
        sc_half(thetas[ 8], sn, cs); cu_gate<3, 2, 16>(R, I, sn, cs);
        sc_half(thetas[ 9], sn, cs); cu_gate<2, 1, 16>(R, I, sn, cs);
        sc_half(thetas[10], sn, cs); cu_gate<1, 0, 16>(R, I, sn, cs);
        sc_half(thetas[11], sn, cs); cu_gate<0, 3, 16>(R, I, sn, cs);
    }
    {
        float snp, csp;
        sc_full(phis[2], snp, csp);
        const f2 C = sp(csp), S = sp(snp), NS = sp(-snp);
#pragma unroll
        for (int m = 24; m < 32; ++m) {
            const f2 r = R[m], ii = I[m];
            R[m] = pk_fma(C, r,  pk_mul(NS, ii));
            I[m] = pk_fma(C, ii, pk_mul(S,  r));
        }
    }

    // final H on wire0 + <Z0>: ev = sum_m Re(v_m * conj(v_{m+16}))
    f2 ev = sp(0.f);
#pragma unroll
    for (int m = 0; m < 16; ++m) {
        ev = pk_fma(R[m], R[m + 16], pk_fma(I[m], I[m + 16], ev));
    }

    float2 o; o.x = ev.x; o.y = ev.y;
    reinterpret_cast<float2*>(out)[t] = o;
}

extern "C" void kernel_launch(void* const* d_in, const int* in_sizes, int n_in,
                              void* d_out, int out_size, void* d_ws, size_t ws_size,
                              hipStream_t stream) {
    const float* x      = (const float*)d_in[0];
    const float* thetas = (const float*)d_in[1];
    const float* phis   = (const float*)d_in[2];
    float* out = (float*)d_out;
    const int P = out_size;               // 16 * 128 * 128 = 262144
    const int T = P >> 1;                 // two patches per thread
    const int threads = 256;
    const int blocks = (T + threads - 1) / threads;
    qsim_kernel<<<blocks, threads, 0, stream>>>(x, thetas, phis, out, P);
}